// Round 4
// baseline (1034.773 us; speedup 1.0000x reference)
//
#include <hip/hip_runtime.h>
#include <hip/hip_bf16.h>
#include <stdint.h>

#define SDIM 2048
#define DDIM 128
#define NT   32   // 2048 / 64 k-tiles

typedef __bf16 bf16x8 __attribute__((ext_vector_type(8)));
typedef float  f32x16 __attribute__((ext_vector_type(16)));

// mask (1,1,S,S) int32 -> transposed bitmask bitsT[kw][row], bit j of word = mask[row][kw*32+j]
__global__ void build_bits_kernel(const int* __restrict__ mask, uint32_t* __restrict__ bitsT) {
  const int id   = blockIdx.x * 4 + (threadIdx.x >> 6);
  const int lane = threadIdx.x & 63;
  const int row  = id >> 5;   // 0..2047
  const int kc   = id & 31;   // 64-wide chunk
  const int m = mask[(size_t)row * SDIM + kc * 64 + lane];
  const unsigned long long b = __ballot(m != 0);
  if (lane == 0)  bitsT[(size_t)(kc * 2    ) * SDIM + row] = (uint32_t)(b & 0xffffffffull);
  if (lane == 32) bitsT[(size_t)(kc * 2 + 1) * SDIM + row] = (uint32_t)(b >> 32);
}

__device__ inline bf16x8 pack8(const float4& a, const float4& b) {
  bf16x8 t;
  t[0]=(__bf16)a.x; t[1]=(__bf16)a.y; t[2]=(__bf16)a.z; t[3]=(__bf16)a.w;
  t[4]=(__bf16)b.x; t[5]=(__bf16)b.y; t[6]=(__bf16)b.z; t[7]=(__bf16)b.w;
  return t;
}

__launch_bounds__(256, 2)
__global__ void attn_kernel(const float* __restrict__ qg, const float* __restrict__ kg,
                            const float* __restrict__ vg, const uint32_t* __restrict__ bitsT,
                            float* __restrict__ outg, float* __restrict__ attng) {
  // double-buffered K (chunk-swizzled), V^T; wave-private P; mask words
  __shared__ __align__(16) __bf16 KR[2][64 * 128];   // 32 KB
  __shared__ __align__(16) __bf16 VTR[2][128 * 64];  // 32 KB
  __shared__ __align__(16) __bf16 PR[4][32 * 32];    // 8 KB
  __shared__ uint32_t MW[2][2][128];                 // 2 KB

  const int bid  = blockIdx.x;
  const int swzb = (bid & 7) * 64 + (bid >> 3);   // XCD-contiguous: 4 heads per XCD
  const int head = swzb >> 4;   // 0..31  (b*16+h)
  const int qb   = swzb & 15;   // 0..15  (128 q-rows each)
  const int tid  = threadIdx.x;
  const int wv   = tid >> 6;
  const int lane = tid & 63;
  const int col  = lane & 31;
  const int hi   = lane >> 5;

  const float* qh = qg + (size_t)head * SDIM * DDIM;
  const float* kh = kg + (size_t)head * SDIM * DDIM;
  const float* vh = vg + (size_t)head * SDIM * DDIM;
  float* outh  = outg  + (size_t)head * SDIM * DDIM;
  float* attnh = attng + (size_t)head * SDIM * SDIM;

  const int qrow0 = qb * 128 + wv * 32;
  const float cscale = 1.4426950408889634f * 0.08838834764831845f; // log2(e)/sqrt(128)
  const uint32_t lanebit = 1u << col;

  // staging mapping: two 32-row halves; row = rh*32 + (tid&31), 16 d per thread
  const int str = tid & 31;
  const int sdb = (tid >> 5) * 16;

  // C/D layout rows for 32x32 mfma (verified): row = (r&3)+8*(r>>2)+4*hi
  int rowl[16];
#pragma unroll
  for (int r = 0; r < 16; ++r) rowl[r] = wv * 32 + (r & 3) + 8 * (r >> 2) + 4 * hi;

  // prefetch registers
  float4 kr[2][4], vrg[2][4];
  uint32_t mwreg;

  auto issueK = [&](int kt) {
#pragma unroll
    for (int rh = 0; rh < 2; ++rh) {
      const float* s = kh + (size_t)(kt * 64 + rh * 32 + str) * DDIM + sdb;
      kr[rh][0] = *(const float4*)(s + 0);
      kr[rh][1] = *(const float4*)(s + 4);
      kr[rh][2] = *(const float4*)(s + 8);
      kr[rh][3] = *(const float4*)(s + 12);
    }
  };
  auto issueV = [&](int kt) {
#pragma unroll
    for (int rh = 0; rh < 2; ++rh) {
      const float* s = vh + (size_t)(kt * 64 + rh * 32 + str) * DDIM + sdb;
      vrg[rh][0] = *(const float4*)(s + 0);
      vrg[rh][1] = *(const float4*)(s + 4);
      vrg[rh][2] = *(const float4*)(s + 8);
      vrg[rh][3] = *(const float4*)(s + 12);
    }
  };
  auto issueM = [&](int kt) {
    mwreg = bitsT[(size_t)(kt * 2 + (tid >> 7)) * SDIM + qb * 128 + (tid & 127)];
  };
  auto writeK = [&](int b) {
#pragma unroll
    for (int rh = 0; rh < 2; ++rh) {
      const int row = rh * 32 + str;
      const int c0 = sdb >> 3;
      *(bf16x8*)&KR[b][row * 128 + (((c0    ) ^ (str & 15))) * 8] = pack8(kr[rh][0], kr[rh][1]);
      *(bf16x8*)&KR[b][row * 128 + (((c0 + 1) ^ (str & 15))) * 8] = pack8(kr[rh][2], kr[rh][3]);
    }
  };
  auto writeV = [&](int b) {
#pragma unroll
    for (int rh = 0; rh < 2; ++rh) {
      float vv[16] = {vrg[rh][0].x, vrg[rh][0].y, vrg[rh][0].z, vrg[rh][0].w,
                      vrg[rh][1].x, vrg[rh][1].y, vrg[rh][1].z, vrg[rh][1].w,
                      vrg[rh][2].x, vrg[rh][2].y, vrg[rh][2].z, vrg[rh][2].w,
                      vrg[rh][3].x, vrg[rh][3].y, vrg[rh][3].z, vrg[rh][3].w};
#pragma unroll
      for (int j = 0; j < 16; ++j) {
        const int d = sdb + j;
        VTR[b][d * 64 + rh * 32 + (((str >> 3) ^ ((d >> 1) & 3)) << 3) + (str & 7)] = (__bf16)vv[j];
      }
    }
  };
  auto writeM = [&](int b) { MW[b][tid >> 7][tid & 127] = mwreg; };

  // ---- Q fragments, in registers for the whole kernel ----
  bf16x8 qf[8];
#pragma unroll
  for (int s = 0; s < 8; ++s) {
    const float* src = qh + (size_t)(qrow0 + col) * DDIM + s * 16 + hi * 8;
    float4 f0 = *(const float4*)(src);
    float4 f1 = *(const float4*)(src + 4);
    qf[s] = pack8(f0, f1);
  }

  float lsum[16];
#pragma unroll
  for (int r = 0; r < 16; ++r) lsum[r] = 0.0f;

  // ================= pass A: softmax denominators =================
  issueK(0); issueM(0);
  writeK(0); writeM(0);
  __syncthreads();
  int cur = 0;
  for (int kt = 0; kt < NT; ++kt) {
    const bool pf = (kt + 1 < NT);
    if (pf) { issueK(kt + 1); issueM(kt + 1); }
#pragma unroll
    for (int h = 0; h < 2; ++h) {
      f32x16 sacc = {};
#pragma unroll
      for (int s = 0; s < 8; ++s) {
        bf16x8 kf = *(const bf16x8*)&KR[cur][(h * 32 + col) * 128 + (((s * 2 + hi) ^ (col & 15))) * 8];
        sacc = __builtin_amdgcn_mfma_f32_32x32x16_bf16(qf[s], kf, sacc, 0, 0, 0);
      }
#pragma unroll
      for (int r = 0; r < 16; ++r) {
        const uint32_t w = MW[cur][h][rowl[r]];
        float pe = __builtin_amdgcn_exp2f(sacc[r] * cscale);
        pe = (w & lanebit) ? pe : 0.0f;
        lsum[r] += pe;
      }
    }
    if (pf) { writeK(cur ^ 1); writeM(cur ^ 1); }
    __syncthreads();
    cur ^= 1;
  }

  // cross-lane row-sum reduction (32 k-cols per half-wave hold the same q-row)
  float loglr[16];
#pragma unroll
  for (int r = 0; r < 16; ++r) {
    float t = lsum[r];
    t += __shfl_xor(t, 1);
    t += __shfl_xor(t, 2);
    t += __shfl_xor(t, 4);
    t += __shfl_xor(t, 8);
    t += __shfl_xor(t, 16);
    loglr[r] = __builtin_amdgcn_logf(fmaxf(t, 1e-30f));  // log2
  }

  f32x16 oacc[4] = {};

  // ================= pass B: write attn + accumulate PV =================
  issueK(0); issueV(0); issueM(0);
  writeK(0); writeV(0); writeM(0);
  __syncthreads();
  cur = 0;
  for (int kt = 0; kt < NT; ++kt) {
    const bool pf = (kt + 1 < NT);
    if (pf) { issueK(kt + 1); issueV(kt + 1); issueM(kt + 1); }
#pragma unroll
    for (int h = 0; h < 2; ++h) {
      f32x16 sacc = {};
#pragma unroll
      for (int s = 0; s < 8; ++s) {
        bf16x8 kf = *(const bf16x8*)&KR[cur][(h * 32 + col) * 128 + (((s * 2 + hi) ^ (col & 15))) * 8];
        sacc = __builtin_amdgcn_mfma_f32_32x32x16_bf16(qf[s], kf, sacc, 0, 0, 0);
      }
#pragma unroll
      for (int r = 0; r < 16; ++r) {
        const uint32_t w = MW[cur][h][rowl[r]];
        float pn = __builtin_amdgcn_exp2f(fmaf(sacc[r], cscale, -loglr[r]));
        pn = (w & lanebit) ? pn : 0.0f;
        __builtin_nontemporal_store(pn,
            &attnh[(size_t)(qb * 128 + rowl[r]) * SDIM + kt * 64 + h * 32 + col]);
        const int qr = rowl[r] - wv * 32;
        PR[wv][qr * 32 + (((col >> 3) ^ ((qr >> 1) & 3)) << 3) + (col & 7)] = (__bf16)pn;
      }
      // PV: out[32q x 128d] += P[32q x 32k] * V[32k x 128d]
#pragma unroll
      for (int ks = 0; ks < 2; ++ks) {
        bf16x8 pfr = *(const bf16x8*)&PR[wv][col * 32 + (((ks * 2 + hi) ^ ((col >> 1) & 3)) << 3)];
#pragma unroll
        for (int dt = 0; dt < 4; ++dt) {
          const int d = dt * 32 + col;
          bf16x8 vf = *(const bf16x8*)&VTR[cur][d * 64 + h * 32 + (((ks * 2 + hi) ^ ((d >> 1) & 3)) << 3)];
          oacc[dt] = __builtin_amdgcn_mfma_f32_32x32x16_bf16(pfr, vf, oacc[dt], 0, 0, 0);
        }
      }
    }
    if (pf) { writeK(cur ^ 1); writeV(cur ^ 1); writeM(cur ^ 1); }
    __syncthreads();
    cur ^= 1;
  }

  // ---- store out ----
#pragma unroll
  for (int dt = 0; dt < 4; ++dt) {
#pragma unroll
    for (int r = 0; r < 16; ++r) {
      __builtin_nontemporal_store(oacc[dt][r],
          &outh[(size_t)(qb * 128 + rowl[r]) * DDIM + dt * 32 + col]);
    }
  }
}

extern "C" void kernel_launch(void* const* d_in, const int* in_sizes, int n_in,
                              void* d_out, int out_size, void* d_ws, size_t ws_size,
                              hipStream_t stream) {
  const float* q   = (const float*)d_in[0];
  const float* k   = (const float*)d_in[1];
  const float* v   = (const float*)d_in[2];
  const int*  mask = (const int*)d_in[3];
  float* outp  = (float*)d_out;
  float* attnp = outp + (size_t)2 * 16 * 2048 * 128;   // out first, then attn
  uint32_t* bitsT = (uint32_t*)d_ws;                   // 64*2048*4 = 512 KB

  hipLaunchKernelGGL(build_bits_kernel, dim3(2048 * 32 / 4), dim3(256), 0, stream, mask, bitsT);
  hipLaunchKernelGGL(attn_kernel, dim3(512), dim3(256), 0, stream,
                     q, k, v, bitsT, outp, attnp);
}